// Round 4
// baseline (201.416 us; speedup 1.0000x reference)
//
#include <hip/hip_runtime.h>
#include <stdint.h>

// CosmosUnpatcher3d: single-level inverse 3D Haar DWT + slice t>=1.
// Input  (fp32): (2, 24, 9, 256, 256) -> 8 bands x 3 channels along axis 1
// Output (fp32): (2, 3, 17, 512, 512)
// out[n,c,to,h,w] = sum_b sign(b; t,h,w) * in[n, 3b+c, t/2, h/2, w/2],
// internal t = to+1; sign = prod over "high" axes of (-1)^(coord&1).
// Net scale c^3*sqrt(8) == 1.0 exactly -> pure +/- 8-way sum.
//
// R3: 2 h-rows per thread -> 16 independent float4 loads in flight per lane
// (2x MLP vs R2's 8), grid 1728 blocks (all co-resident in one fill).

__global__ __launch_bounds__(256, 6) void idwt_haar_kernel(
    const float* __restrict__ in,
    float* __restrict__ out)
{
    const uint32_t flat = blockIdx.x * 256u + threadIdx.x;
    const uint32_t wv = flat & 63u;          // 64 float4s per 256-wide input row
    uint32_t rest = flat >> 6;
    const uint32_t h0 = rest & 127u; rest >>= 7;   // thread handles h0 and h0+128
    const uint32_t t = rest % 9u;  rest /= 9u;
    const uint32_t c = rest % 3u;
    const uint32_t n = rest / 3u;

    // band stride = 3*9*65536 = 1769472 elems; band 0 offset for this (n,c,t)
    const uint32_t base0 = ((n * 24u + c) * 9u + t) * 65536u + wv * 4u;

    // Issue all 16 loads before any use (independent vmcnt slots).
    float a[2][8][4];
#pragma unroll
    for (int uu = 0; uu < 2; ++uu) {
        const uint32_t off = base0 + (h0 + (uu ? 128u : 0u)) * 256u;
#pragma unroll
        for (int b = 0; b < 8; ++b) {
            const float4 v = *reinterpret_cast<const float4*>(
                in + off + (uint32_t)b * 1769472u);
            a[uu][b][0] = v.x; a[uu][b][1] = v.y; a[uu][b][2] = v.z; a[uu][b][3] = v.w;
        }
    }

    const int t_out0 = 2 * (int)t - 1;           // pt=0 slice (skipped when t==0)
    const uint32_t out_nc = (n * 3u + c) * (17u * 262144u) + wv * 8u;

#pragma unroll
    for (int uu = 0; uu < 2; ++uu) {
        // W combine: wst[k][pw][j], k = 2*Tbit + Hbit (band 2k=W-low, 2k+1=W-high)
        float wst[4][2][4];
#pragma unroll
        for (int k = 0; k < 4; ++k)
#pragma unroll
            for (int j = 0; j < 4; ++j) {
                wst[k][0][j] = a[uu][2 * k][j] + a[uu][2 * k + 1][j];
                wst[k][1][j] = a[uu][2 * k][j] - a[uu][2 * k + 1][j];
            }

        // H combine: hst[tb][ph][pw][j]
        float hst[2][2][2][4];
#pragma unroll
        for (int tb = 0; tb < 2; ++tb)
#pragma unroll
            for (int pw = 0; pw < 2; ++pw)
#pragma unroll
                for (int j = 0; j < 4; ++j) {
                    hst[tb][0][pw][j] = wst[2 * tb][pw][j] + wst[2 * tb + 1][pw][j];
                    hst[tb][1][pw][j] = wst[2 * tb][pw][j] - wst[2 * tb + 1][pw][j];
                }

        const uint32_t out_base = out_nc + (h0 + (uu ? 128u : 0u)) * 1024u;

#pragma unroll
        for (int pt = 0; pt < 2; ++pt) {
            const int t_out = t_out0 + pt;
            if (t_out < 0) continue;             // uniform per block (t uniform)
#pragma unroll
            for (int ph = 0; ph < 2; ++ph) {
                float f[8];
#pragma unroll
                for (int j = 0; j < 4; ++j) {
                    float e0 = hst[0][ph][0][j], e1 = hst[1][ph][0][j];
                    float o0 = hst[0][ph][1][j], o1 = hst[1][ph][1][j];
                    f[2 * j]     = (pt == 0) ? (e0 + e1) : (e0 - e1);   // even w
                    f[2 * j + 1] = (pt == 0) ? (o0 + o1) : (o0 - o1);   // odd w
                }
                const uint32_t o = out_base + (uint32_t)t_out * 262144u
                                 + (uint32_t)ph * 512u;
                *reinterpret_cast<float4*>(out + o)      = make_float4(f[0], f[1], f[2], f[3]);
                *reinterpret_cast<float4*>(out + o + 4u) = make_float4(f[4], f[5], f[6], f[7]);
            }
        }
    }
}

extern "C" void kernel_launch(void* const* d_in, const int* in_sizes, int n_in,
                              void* d_out, int out_size, void* d_ws, size_t ws_size,
                              hipStream_t stream) {
    const float* in = (const float*)d_in[0];
    float* out = (float*)d_out;
    // total threads = 2*3*9*128*64 = 442368 = 1728 blocks * 256 (2 h-rows each)
    idwt_haar_kernel<<<dim3(1728), dim3(256), 0, stream>>>(in, out);
}

// Round 5
// 192.709 us; speedup vs baseline: 1.0452x; 1.0452x over previous
//
#include <hip/hip_runtime.h>
#include <stdint.h>

// CosmosUnpatcher3d: single-level inverse 3D Haar DWT + slice t>=1.
// Input  (fp32): (2, 24, 9, 256, 256) -> 8 bands x 3 channels along axis 1
// Output (fp32): (2, 3, 17, 512, 512)
// out[n,c,to,h,w] = sum_b sign(b; t,h,w) * in[n, 3b+c, t/2, h/2, w/2],
// internal t = to+1; sign = prod over "high" axes of (-1)^(coord&1).
// Net scale c^3*sqrt(8) == 1.0 exactly -> pure +/- 8-way sum.
//
// R5: store-coalescing fix. Thread owns an input w-PAIR (float2 per band);
// produces 4 consecutive output floats per (pt,ph) -> every float4 store
// instruction is a contiguous 1KB per wave (4 lanes per 64B line), vs R3/R4's
// half-density 2KB-span stores (2 lanes/line/instr -> 2 line-transactions per
// output line -> write throughput halved).

__global__ __launch_bounds__(256) void idwt_haar_kernel(
    const float* __restrict__ in,
    float* __restrict__ out)
{
    const uint32_t flat = blockIdx.x * 256u + threadIdx.x;
    const uint32_t wq = flat & 127u;         // input w-pair: w = 2wq, 2wq+1
    uint32_t rest = flat >> 7;
    const uint32_t h = rest & 255u; rest >>= 8;
    const uint32_t t = rest % 9u;  rest /= 9u;
    const uint32_t c = rest % 3u;
    const uint32_t n = rest / 3u;

    // band stride = 3*9*65536 = 1769472 elems; band 0 offset for this (n,c,t,h)
    const uint32_t in_off = ((n * 24u + c) * 9u + t) * 65536u + h * 256u + wq * 2u;

    // 8 x float2 loads: 8B/lane, lanes consecutive -> 512B contiguous per instr.
    float a[8][2];
#pragma unroll
    for (int b = 0; b < 8; ++b) {
        const float2 v = *reinterpret_cast<const float2*>(
            in + in_off + (uint32_t)b * 1769472u);
        a[b][0] = v.x; a[b][1] = v.y;
    }

    // W combine: wst[k][m], k = 2*Tbit + Hbit; m = output-w offset 0..3
    // (w_out = 4wq + m; m = 2j + pw from input w-elem j, parity pw)
    float wst[4][4];
#pragma unroll
    for (int k = 0; k < 4; ++k)
#pragma unroll
        for (int j = 0; j < 2; ++j) {
            wst[k][2 * j]     = a[2 * k][j] + a[2 * k + 1][j];
            wst[k][2 * j + 1] = a[2 * k][j] - a[2 * k + 1][j];
        }

    // H combine: hst[tb][ph][m]
    float hst[2][2][4];
#pragma unroll
    for (int tb = 0; tb < 2; ++tb)
#pragma unroll
        for (int m = 0; m < 4; ++m) {
            hst[tb][0][m] = wst[2 * tb][m] + wst[2 * tb + 1][m];
            hst[tb][1][m] = wst[2 * tb][m] - wst[2 * tb + 1][m];
        }

    // T combine + store: 4 float4 stores, each a contiguous 1KB per wave.
    const int t_out0 = 2 * (int)t - 1;        // pt=0 slice (skipped when t==0)
    const uint32_t out_nc = (n * 3u + c) * (17u * 262144u) + h * 1024u + wq * 4u;

#pragma unroll
    for (int pt = 0; pt < 2; ++pt) {
        const int t_out = t_out0 + pt;
        if (t_out < 0) continue;              // uniform per block (t uniform)
#pragma unroll
        for (int ph = 0; ph < 2; ++ph) {
            float f[4];
#pragma unroll
            for (int m = 0; m < 4; ++m) {
                f[m] = (pt == 0) ? (hst[0][ph][m] + hst[1][ph][m])
                                 : (hst[0][ph][m] - hst[1][ph][m]);
            }
            const uint32_t o = out_nc + (uint32_t)t_out * 262144u
                             + (uint32_t)ph * 512u;
            *reinterpret_cast<float4*>(out + o) = make_float4(f[0], f[1], f[2], f[3]);
        }
    }
}

extern "C" void kernel_launch(void* const* d_in, const int* in_sizes, int n_in,
                              void* d_out, int out_size, void* d_ws, size_t ws_size,
                              hipStream_t stream) {
    const float* in = (const float*)d_in[0];
    float* out = (float*)d_out;
    // total threads = 2*3*9*256*128 = 1769472 = 6912 blocks * 256
    idwt_haar_kernel<<<dim3(6912), dim3(256), 0, stream>>>(in, out);
}

// Round 6
// 192.173 us; speedup vs baseline: 1.0481x; 1.0028x over previous
//
#include <hip/hip_runtime.h>
#include <stdint.h>

// CosmosUnpatcher3d: single-level inverse 3D Haar DWT + slice t>=1.
// Input  (fp32): (2, 24, 9, 256, 256) -> 8 bands x 3 channels along axis 1
// Output (fp32): (2, 3, 17, 512, 512)
// out[n,c,to,h,w] = sum_b sign(b; t,h,w) * in[n, 3b+c, t/2, h/2, w/2],
// internal t = to+1; sign = prod over "high" axes of (-1)^(coord&1).
// Net scale c^3*sqrt(8) == 1.0 exactly -> pure +/- 8-way sum.
//
// R6: R5 layout (dense float2 loads, dense float4 stores) + NONTEMPORAL
// stores: output lines are L3-resident-dirty (harness poison fill + memset
// immediately before); allocating stores pay evict-dirty + allocate per line.
// nt stores stream past the cache like the 6.8 TB/s fill kernel does.

typedef float f4nt __attribute__((ext_vector_type(4)));

__global__ __launch_bounds__(256) void idwt_haar_kernel(
    const float* __restrict__ in,
    float* __restrict__ out)
{
    const uint32_t flat = blockIdx.x * 256u + threadIdx.x;
    const uint32_t wq = flat & 127u;         // input w-pair: w = 2wq, 2wq+1
    uint32_t rest = flat >> 7;
    const uint32_t h = rest & 255u; rest >>= 8;
    const uint32_t t = rest % 9u;  rest /= 9u;
    const uint32_t c = rest % 3u;
    const uint32_t n = rest / 3u;

    // band stride = 3*9*65536 = 1769472 elems; band 0 offset for this (n,c,t,h)
    const uint32_t in_off = ((n * 24u + c) * 9u + t) * 65536u + h * 256u + wq * 2u;

    // 8 x float2 loads: 8B/lane, lanes consecutive -> 512B contiguous per instr.
    float a[8][2];
#pragma unroll
    for (int b = 0; b < 8; ++b) {
        const float2 v = *reinterpret_cast<const float2*>(
            in + in_off + (uint32_t)b * 1769472u);
        a[b][0] = v.x; a[b][1] = v.y;
    }

    // W combine: wst[k][m], k = 2*Tbit + Hbit; m = output-w offset 0..3
    float wst[4][4];
#pragma unroll
    for (int k = 0; k < 4; ++k)
#pragma unroll
        for (int j = 0; j < 2; ++j) {
            wst[k][2 * j]     = a[2 * k][j] + a[2 * k + 1][j];
            wst[k][2 * j + 1] = a[2 * k][j] - a[2 * k + 1][j];
        }

    // H combine: hst[tb][ph][m]
    float hst[2][2][4];
#pragma unroll
    for (int tb = 0; tb < 2; ++tb)
#pragma unroll
        for (int m = 0; m < 4; ++m) {
            hst[tb][0][m] = wst[2 * tb][m] + wst[2 * tb + 1][m];
            hst[tb][1][m] = wst[2 * tb][m] - wst[2 * tb + 1][m];
        }

    // T combine + nontemporal store: 4 float4 stores, contiguous 1KB per wave.
    const int t_out0 = 2 * (int)t - 1;        // pt=0 slice (skipped when t==0)
    const uint32_t out_nc = (n * 3u + c) * (17u * 262144u) + h * 1024u + wq * 4u;

#pragma unroll
    for (int pt = 0; pt < 2; ++pt) {
        const int t_out = t_out0 + pt;
        if (t_out < 0) continue;              // uniform per block (t uniform)
#pragma unroll
        for (int ph = 0; ph < 2; ++ph) {
            f4nt f;
#pragma unroll
            for (int m = 0; m < 4; ++m) {
                f[m] = (pt == 0) ? (hst[0][ph][m] + hst[1][ph][m])
                                 : (hst[0][ph][m] - hst[1][ph][m]);
            }
            const uint32_t o = out_nc + (uint32_t)t_out * 262144u
                             + (uint32_t)ph * 512u;
            __builtin_nontemporal_store(f, reinterpret_cast<f4nt*>(out + o));
        }
    }
}

extern "C" void kernel_launch(void* const* d_in, const int* in_sizes, int n_in,
                              void* d_out, int out_size, void* d_ws, size_t ws_size,
                              hipStream_t stream) {
    const float* in = (const float*)d_in[0];
    float* out = (float*)d_out;
    // total threads = 2*3*9*256*128 = 1769472 = 6912 blocks * 256
    idwt_haar_kernel<<<dim3(6912), dim3(256), 0, stream>>>(in, out);
}